// Round 4
// baseline (741.424 us; speedup 1.0000x reference)
//
#include <hip/hip_runtime.h>

#define NNODES 100000
#define NEDGES 1600000
#define FIN 128
#define FH 64
#define FOUT 32
#define NGRAPH 128
#define EPSV 1e-5f

#define SCAN_BT 256
#define NBLK ((NNODES + SCAN_BT - 1) / SCAN_BT)  // 391

// ---------------- degree / normalization ----------------

__global__ void k_init_deg(float* __restrict__ deg) {
  int i = blockIdx.x * blockDim.x + threadIdx.x;
  if (i < NNODES) deg[i] = 1.0f;  // self-loop contributes 1
}

__global__ void k_deg_accum(const int* __restrict__ dst, float* __restrict__ deg) {
  int i = blockIdx.x * blockDim.x + threadIdx.x;
  if (i < NEDGES) atomicAdd(&deg[dst[i]], 1.0f);
}

__global__ void k_rsqrt(float* __restrict__ deg) {
  int i = blockIdx.x * blockDim.x + threadIdx.x;
  if (i < NNODES) deg[i] = rsqrtf(deg[i]);  // deg >= 1 always
}

// ---------------- CSR build: hierarchical exclusive scan of in-degrees ------

__global__ void k_blocksum(const float* __restrict__ deg, int* __restrict__ bsum) {
  __shared__ int ls[SCAN_BT];
  int b = blockIdx.x, t = threadIdx.x;
  int i = b * SCAN_BT + t;
  ls[t] = (i < NNODES) ? (int)deg[i] - 1 : 0;
  __syncthreads();
  for (int s = SCAN_BT / 2; s > 0; s >>= 1) {
    if (t < s) ls[t] += ls[t + s];
    __syncthreads();
  }
  if (t == 0) bsum[b] = ls[0];
}

__global__ void k_scan_bsums(const int* __restrict__ bsum, int* __restrict__ boff) {
  __shared__ int ls[512];
  int t = threadIdx.x;
  int v = (t < NBLK) ? bsum[t] : 0;
  ls[t] = v;
  __syncthreads();
  for (int s = 1; s < 512; s <<= 1) {
    int add = (t >= s) ? ls[t - s] : 0;
    __syncthreads();
    ls[t] += add;
    __syncthreads();
  }
  if (t < NBLK) boff[t] = ls[t] - v;  // exclusive
}

__global__ void k_scan_final(const float* __restrict__ deg, const int* __restrict__ boff,
                             int* __restrict__ off) {
  __shared__ int ls[SCAN_BT];
  int b = blockIdx.x, t = threadIdx.x;
  int i = b * SCAN_BT + t;
  int v = (i < NNODES) ? (int)deg[i] - 1 : 0;
  ls[t] = v;
  __syncthreads();
  for (int s = 1; s < SCAN_BT; s <<= 1) {
    int add = (t >= s) ? ls[t - s] : 0;
    __syncthreads();
    ls[t] += add;
    __syncthreads();
  }
  if (i < NNODES) off[i] = boff[b] + ls[t] - v;  // exclusive offset
  if (i == NNODES - 1) off[NNODES] = boff[b] + ls[t];
}

__global__ void k_fill(const int* __restrict__ src, const int* __restrict__ dst,
                       const int* __restrict__ off, int* __restrict__ cursor,
                       int* __restrict__ csr) {
  int i = blockIdx.x * blockDim.x + threadIdx.x;
  if (i < NEDGES) {
    int d = dst[i];
    int p = atomicAdd(&cursor[d], 1);
    csr[off[d] + p] = src[i];
  }
}

// ---------------- skinny GEMM: out[N x 64] = act(A[N x K]) @ W[K x 64] -------
// Epilogue scales by dis[row] (symmetric norm folded into the stored matrix).

template <int K, bool BN>
__global__ void k_gemm(const float* __restrict__ A, const float* __restrict__ W,
                       const float* __restrict__ sc, const float* __restrict__ sh,
                       const float* __restrict__ dis, float* __restrict__ out) {
  int row = blockIdx.x * blockDim.x + threadIdx.x;
  if (row >= NNODES) return;
  float acc[FH];
#pragma unroll
  for (int j = 0; j < FH; ++j) acc[j] = 0.0f;
  const float* a = A + (long long)row * K;
  for (int k = 0; k < K; k += 4) {
    float4 x4 = *(const float4*)(a + k);
    float xs[4] = {x4.x, x4.y, x4.z, x4.w};
#pragma unroll
    for (int kk = 0; kk < 4; ++kk) {
      float xv = xs[kk];
      if (BN) {
        xv = fmaf(xv, sc[k + kk], sh[k + kk]);
        xv = fmaxf(xv, 0.0f);
      }
      const float* wr = W + (k + kk) * FH;
#pragma unroll
      for (int j = 0; j < FH; ++j) acc[j] = fmaf(xv, wr[j], acc[j]);
    }
  }
  float d = dis[row];
  float* o = out + (long long)row * FH;
#pragma unroll
  for (int j = 0; j < FH; j += 4) {
    float4 v = {acc[j] * d, acc[j + 1] * d, acc[j + 2] * d, acc[j + 3] * d};
    *(float4*)(o + j) = v;
  }
}

// ---------------- aggregation: out[d] = dis[d] * (hs[d] + sum hs[csr]) ------
// One wave handles NPN destination nodes concurrently -> NPN independent load
// chains (memory-level parallelism); bounds checks are wave-uniform.
// BN statistics fused into the epilogue.

#define NPN 4

__global__ void k_gather(const float* __restrict__ hs, const int* __restrict__ csr,
                         const int* __restrict__ off, const float* __restrict__ dis,
                         float* __restrict__ out, float* __restrict__ stats) {
  __shared__ float ls[2 * FH];
  int tid = threadIdx.x;
  if (tid < 2 * FH) ls[tid] = 0.0f;
  __syncthreads();
  int lane = tid & 63;
  int wid = (blockIdx.x * blockDim.x + tid) >> 6;
  int nw = (gridDim.x * blockDim.x) >> 6;
  float s1 = 0.0f, s2 = 0.0f;
  const int ngroups = (NNODES + NPN - 1) / NPN;
  for (int grp = wid; grp < ngroups; grp += nw) {
    int d0 = grp * NPN;
    int b[NPN], cnt[NPN];
    float acc[NPN];
#pragma unroll
    for (int i = 0; i < NPN; ++i) {
      int d = d0 + i;
      if (d < NNODES) {
        b[i] = off[d];
        cnt[i] = off[d + 1] - b[i];
        acc[i] = hs[(long long)d * FH + lane];  // self-loop term
      } else {
        b[i] = 0;
        cnt[i] = 0;
        acc[i] = 0.0f;
      }
    }
    int maxd = 0;
#pragma unroll
    for (int i = 0; i < NPN; ++i) maxd = max(maxd, cnt[i]);
    for (int k = 0; k < maxd; ++k) {
#pragma unroll
      for (int i = 0; i < NPN; ++i) {
        if (k < cnt[i]) {  // wave-uniform branch
          int s = csr[b[i] + k];
          acc[i] += hs[(long long)s * FH + lane];
        }
      }
    }
#pragma unroll
    for (int i = 0; i < NPN; ++i) {
      int d = d0 + i;
      if (d < NNODES) {
        float o = acc[i] * dis[d];
        out[(long long)d * FH + lane] = o;
        s1 += o;
        s2 += o * o;
      }
    }
  }
  atomicAdd(&ls[lane], s1);
  atomicAdd(&ls[FH + lane], s2);
  __syncthreads();
  if (tid < 2 * FH) atomicAdd(&stats[tid], ls[tid]);
}

__global__ void k_bn_finalize(const float* __restrict__ stats, const float* __restrict__ gamma,
                              const float* __restrict__ beta, float* __restrict__ scsh) {
  int f = threadIdx.x;
  if (f < FH) {
    float mean = stats[f] * (1.0f / NNODES);
    float var = stats[FH + f] * (1.0f / NNODES) - mean * mean;
    float s = gamma[f] * rsqrtf(var + EPSV);
    scsh[f] = s;
    scsh[FH + f] = beta[f] - mean * s;  // bias b cancels in training-mode BN
  }
}

// ---------------- pooling (applies BN2+ReLU on load) ----------------

#define POOL_WAVES 1024

__global__ void k_pool(const float* __restrict__ h, const int* __restrict__ batch,
                       const float* __restrict__ scsh, float* __restrict__ pooled,
                       float* __restrict__ cnt) {
  const int CHUNK = (NNODES + POOL_WAVES - 1) / POOL_WAVES;
  int lane = threadIdx.x & 63;
  int wid = (blockIdx.x * blockDim.x + threadIdx.x) >> 6;
  int start = wid * CHUNK;
  if (start >= NNODES) return;
  int end = min(start + CHUNK, NNODES);
  float sc = scsh[lane], sh = scsh[FH + lane];
  int cur = batch[start];  // wave-uniform
  float acc = 0.0f;
  int cl = 0;
  for (int n = start; n < end; ++n) {
    int g = batch[n];
    if (g != cur) {  // uniform branch
      atomicAdd(&pooled[cur * FH + lane], acc);
      if (lane == 0) atomicAdd(&cnt[cur], (float)cl);
      acc = 0.0f;
      cl = 0;
      cur = g;
    }
    float v = fmaf(h[(long long)n * FH + lane], sc, sh);
    acc += fmaxf(v, 0.0f);
    ++cl;
  }
  atomicAdd(&pooled[cur * FH + lane], acc);
  if (lane == 0) atomicAdd(&cnt[cur], (float)cl);
}

// ---------------- final linear: out[G x 32] = (pooled/cnt) @ linW + linb -----

__global__ void k_final(const float* __restrict__ pooled, const float* __restrict__ cnt,
                        const float* __restrict__ linW, const float* __restrict__ linb,
                        float* __restrict__ out) {
  int t = blockIdx.x * blockDim.x + threadIdx.x;
  if (t >= NGRAPH * FOUT) return;
  int g = t / FOUT, o = t % FOUT;
  float inv = 1.0f / fmaxf(cnt[g], 1.0f);
  float acc = linb[o];
#pragma unroll
  for (int k = 0; k < FH; ++k) acc = fmaf(pooled[g * FH + k] * inv, linW[k * FOUT + o], acc);
  out[t] = acc;
}

extern "C" void kernel_launch(void* const* d_in, const int* in_sizes, int n_in,
                              void* d_out, int out_size, void* d_ws, size_t ws_size,
                              hipStream_t stream) {
  const float* x = (const float*)d_in[0];
  const int* edge_index = (const int*)d_in[1];
  const int* batch = (const int*)d_in[2];
  const float* W1 = (const float*)d_in[3];
  // d_in[4] = b1 (cancels in BN), d_in[6] = b2 (cancels in BN)
  const float* W2 = (const float*)d_in[5];
  const float* gamma = (const float*)d_in[7];
  const float* beta = (const float*)d_in[8];
  const float* linW = (const float*)d_in[9];
  const float* linb = (const float*)d_in[10];
  float* out = (float*)d_out;

  const int* esrc = edge_index;           // edge_index[0, :]
  const int* edst = edge_index + NEDGES;  // edge_index[1, :]

  // workspace layout
  float* bufA = (float*)d_ws;                   // N*64 (GEMM output, dis-scaled)
  float* bufB = bufA + (long long)NNODES * FH;  // N*64 (aggregation output)
  float* dis = bufB + (long long)NNODES * FH;   // N (deg -> rsqrt(deg))
  int* off = (int*)(dis + NNODES);              // N+1
  int* csr = off + (NNODES + 1);                // E
  int* bsum = csr + NEDGES;                     // NBLK
  int* boff = bsum + NBLK;                      // NBLK
  int* cursor = boff + NBLK;                    // N   --- zeroed region start
  float* stats1 = (float*)(cursor + NNODES);    // 128
  float* scsh1 = stats1 + 2 * FH;               // 128
  float* stats2 = scsh1 + 2 * FH;               // 128
  float* scsh2 = stats2 + 2 * FH;               // 128
  float* pooled = scsh2 + 2 * FH;               // G*64
  float* cnt = pooled + NGRAPH * FH;            // G   --- zeroed region end

  const int BT = 256;
  const int gN = (NNODES + BT - 1) / BT;
  const int gE = (NEDGES + BT - 1) / BT;

  // zero cursor + stats + pooled + cnt in one shot (contiguous)
  hipMemsetAsync(cursor, 0,
                 (size_t)(NNODES + 4 * 2 * FH + NGRAPH * FH + NGRAPH) * sizeof(float), stream);

  // degrees (raw), CSR offsets, then rsqrt in place, then fill
  k_init_deg<<<gN, BT, 0, stream>>>(dis);
  k_deg_accum<<<gE, BT, 0, stream>>>(edst, dis);
  k_blocksum<<<NBLK, SCAN_BT, 0, stream>>>(dis, bsum);
  k_scan_bsums<<<1, 512, 0, stream>>>(bsum, boff);
  k_scan_final<<<NBLK, SCAN_BT, 0, stream>>>(dis, boff, off);
  k_rsqrt<<<gN, BT, 0, stream>>>(dis);
  k_fill<<<gE, BT, 0, stream>>>(esrc, edst, off, cursor, csr);

  // layer 1
  k_gemm<FIN, false><<<gN, BT, 0, stream>>>(x, W1, nullptr, nullptr, dis, bufA);
  k_gather<<<2048, BT, 0, stream>>>(bufA, csr, off, dis, bufB, stats1);
  k_bn_finalize<<<1, 64, 0, stream>>>(stats1, gamma, beta, scsh1);

  // layer 2 (BN1+ReLU fused into GEMM input load)
  k_gemm<FH, true><<<gN, BT, 0, stream>>>(bufB, W2, scsh1, scsh1 + FH, dis, bufA);
  k_gather<<<2048, BT, 0, stream>>>(bufA, csr, off, dis, bufB, stats2);
  k_bn_finalize<<<1, 64, 0, stream>>>(stats2, gamma, beta, scsh2);

  // pooling (BN2+ReLU fused) + final linear
  k_pool<<<POOL_WAVES * 64 / BT, BT, 0, stream>>>(bufB, batch, scsh2, pooled, cnt);
  k_final<<<(NGRAPH * FOUT + BT - 1) / BT, BT, 0, stream>>>(pooled, cnt, linW, linb, out);
}

// Round 5
// 582.507 us; speedup vs baseline: 1.2728x; 1.2728x over previous
//
#include <hip/hip_runtime.h>

#define NNODES 100000
#define NEDGES 1600000
#define FIN 128
#define FH 64
#define FOUT 32
#define NGRAPH 128
#define EPSV 1e-5f

#define SCAN_BT 256
#define NBLK ((NNODES + SCAN_BT - 1) / SCAN_BT)  // 391

// ---------------- degree / normalization ----------------

__global__ void k_init_deg(float* __restrict__ deg) {
  int i = blockIdx.x * blockDim.x + threadIdx.x;
  if (i < NNODES) deg[i] = 1.0f;  // self-loop contributes 1
}

__global__ void k_deg_accum(const int* __restrict__ dst, float* __restrict__ deg) {
  int i = blockIdx.x * blockDim.x + threadIdx.x;
  if (i < NEDGES) atomicAdd(&deg[dst[i]], 1.0f);
}

__global__ void k_rsqrt(float* __restrict__ deg) {
  int i = blockIdx.x * blockDim.x + threadIdx.x;
  if (i < NNODES) deg[i] = rsqrtf(deg[i]);  // deg >= 1 always
}

// ---------------- CSR build: hierarchical exclusive scan of in-degrees ------

__global__ void k_blocksum(const float* __restrict__ deg, int* __restrict__ bsum) {
  __shared__ int ls[SCAN_BT];
  int b = blockIdx.x, t = threadIdx.x;
  int i = b * SCAN_BT + t;
  ls[t] = (i < NNODES) ? (int)deg[i] - 1 : 0;
  __syncthreads();
  for (int s = SCAN_BT / 2; s > 0; s >>= 1) {
    if (t < s) ls[t] += ls[t + s];
    __syncthreads();
  }
  if (t == 0) bsum[b] = ls[0];
}

__global__ void k_scan_bsums(const int* __restrict__ bsum, int* __restrict__ boff) {
  __shared__ int ls[512];
  int t = threadIdx.x;
  int v = (t < NBLK) ? bsum[t] : 0;
  ls[t] = v;
  __syncthreads();
  for (int s = 1; s < 512; s <<= 1) {
    int add = (t >= s) ? ls[t - s] : 0;
    __syncthreads();
    ls[t] += add;
    __syncthreads();
  }
  if (t < NBLK) boff[t] = ls[t] - v;  // exclusive
}

__global__ void k_scan_final(const float* __restrict__ deg, const int* __restrict__ boff,
                             int* __restrict__ off) {
  __shared__ int ls[SCAN_BT];
  int b = blockIdx.x, t = threadIdx.x;
  int i = b * SCAN_BT + t;
  int v = (i < NNODES) ? (int)deg[i] - 1 : 0;
  ls[t] = v;
  __syncthreads();
  for (int s = 1; s < SCAN_BT; s <<= 1) {
    int add = (t >= s) ? ls[t - s] : 0;
    __syncthreads();
    ls[t] += add;
    __syncthreads();
  }
  if (i < NNODES) off[i] = boff[b] + ls[t] - v;  // exclusive offset
  if (i == NNODES - 1) off[NNODES] = boff[b] + ls[t];
}

__global__ void k_fill(const int* __restrict__ src, const int* __restrict__ dst,
                       const int* __restrict__ off, int* __restrict__ cursor,
                       int* __restrict__ csr) {
  int i = blockIdx.x * blockDim.x + threadIdx.x;
  if (i < NEDGES) {
    int d = dst[i];
    int p = atomicAdd(&cursor[d], 1);
    csr[off[d] + p] = src[i];
  }
}

// ---------------- skinny GEMM: out[N x 64] = act(A[N x K]) @ W[K x 64] -------
// Epilogue scales by dis[row] (symmetric norm folded into the stored matrix).

template <int K, bool BN>
__global__ void k_gemm(const float* __restrict__ A, const float* __restrict__ W,
                       const float* __restrict__ sc, const float* __restrict__ sh,
                       const float* __restrict__ dis, float* __restrict__ out) {
  int row = blockIdx.x * blockDim.x + threadIdx.x;
  if (row >= NNODES) return;
  float acc[FH];
#pragma unroll
  for (int j = 0; j < FH; ++j) acc[j] = 0.0f;
  const float* a = A + (long long)row * K;
  for (int k = 0; k < K; k += 4) {
    float4 x4 = *(const float4*)(a + k);
    float xs[4] = {x4.x, x4.y, x4.z, x4.w};
#pragma unroll
    for (int kk = 0; kk < 4; ++kk) {
      float xv = xs[kk];
      if (BN) {
        xv = fmaf(xv, sc[k + kk], sh[k + kk]);
        xv = fmaxf(xv, 0.0f);
      }
      const float* wr = W + (k + kk) * FH;
#pragma unroll
      for (int j = 0; j < FH; ++j) acc[j] = fmaf(xv, wr[j], acc[j]);
    }
  }
  float d = dis[row];
  float* o = out + (long long)row * FH;
#pragma unroll
  for (int j = 0; j < FH; j += 4) {
    float4 v = {acc[j] * d, acc[j + 1] * d, acc[j + 2] * d, acc[j + 3] * d};
    *(float4*)(o + j) = v;
  }
}

// ---------------- aggregation: out[d] = dis[d] * (hs[d] + sum hs[csr]) ------
// One wave per dst node. Neighbor loop is branchless unroll-by-4: the 4 csr
// reads and 4 hs row-loads are independent -> ~4 outstanding 256B gathers per
// wave. Tail lanes clamp the index to e-1 (valid) and mask the add via select
// (no control flow between loads). BN statistics fused into the epilogue.

__global__ void k_gather(const float* __restrict__ hs, const int* __restrict__ csr,
                         const int* __restrict__ off, const float* __restrict__ dis,
                         float* __restrict__ out, float* __restrict__ stats) {
  __shared__ float ls[2 * FH];
  int tid = threadIdx.x;
  if (tid < 2 * FH) ls[tid] = 0.0f;
  __syncthreads();
  int lane = tid & 63;
  int wid = (blockIdx.x * blockDim.x + tid) >> 6;
  int nw = (gridDim.x * blockDim.x) >> 6;
  float s1 = 0.0f, s2 = 0.0f;
  for (int d = wid; d < NNODES; d += nw) {
    float acc = hs[(long long)d * FH + lane];  // self-loop term
    int b = off[d], e = off[d + 1];
    for (int k = b; k < e; k += 4) {
      int last = e - 1;
      int i1 = min(k + 1, last), i2 = min(k + 2, last), i3 = min(k + 3, last);
      int s0v = csr[k], s1v = csr[i1], s2v = csr[i2], s3v = csr[i3];
      float v0 = hs[(long long)s0v * FH + lane];
      float v1 = hs[(long long)s1v * FH + lane];
      float v2 = hs[(long long)s2v * FH + lane];
      float v3 = hs[(long long)s3v * FH + lane];
      v1 = (k + 1 < e) ? v1 : 0.0f;
      v2 = (k + 2 < e) ? v2 : 0.0f;
      v3 = (k + 3 < e) ? v3 : 0.0f;
      acc += (v0 + v1) + (v2 + v3);
    }
    float o = acc * dis[d];
    out[(long long)d * FH + lane] = o;
    s1 += o;
    s2 += o * o;
  }
  atomicAdd(&ls[lane], s1);
  atomicAdd(&ls[FH + lane], s2);
  __syncthreads();
  if (tid < 2 * FH) atomicAdd(&stats[tid], ls[tid]);
}

__global__ void k_bn_finalize(const float* __restrict__ stats, const float* __restrict__ gamma,
                              const float* __restrict__ beta, float* __restrict__ scsh) {
  int f = threadIdx.x;
  if (f < FH) {
    float mean = stats[f] * (1.0f / NNODES);
    float var = stats[FH + f] * (1.0f / NNODES) - mean * mean;
    float s = gamma[f] * rsqrtf(var + EPSV);
    scsh[f] = s;
    scsh[FH + f] = beta[f] - mean * s;  // bias b cancels in training-mode BN
  }
}

// ---------------- pooling (applies BN2+ReLU on load) ----------------

#define POOL_WAVES 1024

__global__ void k_pool(const float* __restrict__ h, const int* __restrict__ batch,
                       const float* __restrict__ scsh, float* __restrict__ pooled,
                       float* __restrict__ cnt) {
  const int CHUNK = (NNODES + POOL_WAVES - 1) / POOL_WAVES;
  int lane = threadIdx.x & 63;
  int wid = (blockIdx.x * blockDim.x + threadIdx.x) >> 6;
  int start = wid * CHUNK;
  if (start >= NNODES) return;
  int end = min(start + CHUNK, NNODES);
  float sc = scsh[lane], sh = scsh[FH + lane];
  int cur = batch[start];  // wave-uniform
  float acc = 0.0f;
  int cl = 0;
  for (int n = start; n < end; ++n) {
    int g = batch[n];
    if (g != cur) {  // uniform branch
      atomicAdd(&pooled[cur * FH + lane], acc);
      if (lane == 0) atomicAdd(&cnt[cur], (float)cl);
      acc = 0.0f;
      cl = 0;
      cur = g;
    }
    float v = fmaf(h[(long long)n * FH + lane], sc, sh);
    acc += fmaxf(v, 0.0f);
    ++cl;
  }
  atomicAdd(&pooled[cur * FH + lane], acc);
  if (lane == 0) atomicAdd(&cnt[cur], (float)cl);
}

// ---------------- final linear: out[G x 32] = (pooled/cnt) @ linW + linb -----

__global__ void k_final(const float* __restrict__ pooled, const float* __restrict__ cnt,
                        const float* __restrict__ linW, const float* __restrict__ linb,
                        float* __restrict__ out) {
  int t = blockIdx.x * blockDim.x + threadIdx.x;
  if (t >= NGRAPH * FOUT) return;
  int g = t / FOUT, o = t % FOUT;
  float inv = 1.0f / fmaxf(cnt[g], 1.0f);
  float acc = linb[o];
#pragma unroll
  for (int k = 0; k < FH; ++k) acc = fmaf(pooled[g * FH + k] * inv, linW[k * FOUT + o], acc);
  out[t] = acc;
}

extern "C" void kernel_launch(void* const* d_in, const int* in_sizes, int n_in,
                              void* d_out, int out_size, void* d_ws, size_t ws_size,
                              hipStream_t stream) {
  const float* x = (const float*)d_in[0];
  const int* edge_index = (const int*)d_in[1];
  const int* batch = (const int*)d_in[2];
  const float* W1 = (const float*)d_in[3];
  // d_in[4] = b1 (cancels in BN), d_in[6] = b2 (cancels in BN)
  const float* W2 = (const float*)d_in[5];
  const float* gamma = (const float*)d_in[7];
  const float* beta = (const float*)d_in[8];
  const float* linW = (const float*)d_in[9];
  const float* linb = (const float*)d_in[10];
  float* out = (float*)d_out;

  const int* esrc = edge_index;           // edge_index[0, :]
  const int* edst = edge_index + NEDGES;  // edge_index[1, :]

  // workspace layout
  float* bufA = (float*)d_ws;                   // N*64 (GEMM output, dis-scaled)
  float* bufB = bufA + (long long)NNODES * FH;  // N*64 (aggregation output)
  float* dis = bufB + (long long)NNODES * FH;   // N (deg -> rsqrt(deg))
  int* off = (int*)(dis + NNODES);              // N+1
  int* csr = off + (NNODES + 1);                // E
  int* bsum = csr + NEDGES;                     // NBLK
  int* boff = bsum + NBLK;                      // NBLK
  int* cursor = boff + NBLK;                    // N   --- zeroed region start
  float* stats1 = (float*)(cursor + NNODES);    // 128
  float* scsh1 = stats1 + 2 * FH;               // 128
  float* stats2 = scsh1 + 2 * FH;               // 128
  float* scsh2 = stats2 + 2 * FH;               // 128
  float* pooled = scsh2 + 2 * FH;               // G*64
  float* cnt = pooled + NGRAPH * FH;            // G   --- zeroed region end

  const int BT = 256;
  const int gN = (NNODES + BT - 1) / BT;
  const int gE = (NEDGES + BT - 1) / BT;

  // zero cursor + stats + pooled + cnt in one shot (contiguous)
  hipMemsetAsync(cursor, 0,
                 (size_t)(NNODES + 4 * 2 * FH + NGRAPH * FH + NGRAPH) * sizeof(float), stream);

  // degrees (raw), CSR offsets, then rsqrt in place, then fill
  k_init_deg<<<gN, BT, 0, stream>>>(dis);
  k_deg_accum<<<gE, BT, 0, stream>>>(edst, dis);
  k_blocksum<<<NBLK, SCAN_BT, 0, stream>>>(dis, bsum);
  k_scan_bsums<<<1, 512, 0, stream>>>(bsum, boff);
  k_scan_final<<<NBLK, SCAN_BT, 0, stream>>>(dis, boff, off);
  k_rsqrt<<<gN, BT, 0, stream>>>(dis);
  k_fill<<<gE, BT, 0, stream>>>(esrc, edst, off, cursor, csr);

  // layer 1
  k_gemm<FIN, false><<<gN, BT, 0, stream>>>(x, W1, nullptr, nullptr, dis, bufA);
  k_gather<<<2048, BT, 0, stream>>>(bufA, csr, off, dis, bufB, stats1);
  k_bn_finalize<<<1, 64, 0, stream>>>(stats1, gamma, beta, scsh1);

  // layer 2 (BN1+ReLU fused into GEMM input load)
  k_gemm<FH, true><<<gN, BT, 0, stream>>>(bufB, W2, scsh1, scsh1 + FH, dis, bufA);
  k_gather<<<2048, BT, 0, stream>>>(bufA, csr, off, dis, bufB, stats2);
  k_bn_finalize<<<1, 64, 0, stream>>>(stats2, gamma, beta, scsh2);

  // pooling (BN2+ReLU fused) + final linear
  k_pool<<<POOL_WAVES * 64 / BT, BT, 0, stream>>>(bufB, batch, scsh2, pooled, cnt);
  k_final<<<(NGRAPH * FOUT + BT - 1) / BT, BT, 0, stream>>>(pooled, cnt, linW, linb, out);
}

// Round 6
// 578.013 us; speedup vs baseline: 1.2827x; 1.0078x over previous
//
#include <hip/hip_runtime.h>

#define NNODES 100000
#define NEDGES 1600000
#define FIN 128
#define FH 64
#define FOUT 32
#define NGRAPH 128
#define EPSV 1e-5f

#define SCAN_BT 256
#define NBLK ((NNODES + SCAN_BT - 1) / SCAN_BT)  // 391

// ---------------- degree / normalization ----------------

__global__ void k_init_deg(float* __restrict__ deg) {
  int i = blockIdx.x * blockDim.x + threadIdx.x;
  if (i < NNODES) deg[i] = 1.0f;  // self-loop contributes 1
}

__global__ void k_deg_accum(const int* __restrict__ dst, float* __restrict__ deg) {
  int i = blockIdx.x * blockDim.x + threadIdx.x;
  if (i < NEDGES) atomicAdd(&deg[dst[i]], 1.0f);
}

__global__ void k_rsqrt(float* __restrict__ deg) {
  int i = blockIdx.x * blockDim.x + threadIdx.x;
  if (i < NNODES) deg[i] = rsqrtf(deg[i]);  // deg >= 1 always
}

// ---------------- CSR build: hierarchical exclusive scan of in-degrees ------

__global__ void k_blocksum(const float* __restrict__ deg, int* __restrict__ bsum) {
  __shared__ int ls[SCAN_BT];
  int b = blockIdx.x, t = threadIdx.x;
  int i = b * SCAN_BT + t;
  ls[t] = (i < NNODES) ? (int)deg[i] - 1 : 0;
  __syncthreads();
  for (int s = SCAN_BT / 2; s > 0; s >>= 1) {
    if (t < s) ls[t] += ls[t + s];
    __syncthreads();
  }
  if (t == 0) bsum[b] = ls[0];
}

__global__ void k_scan_bsums(const int* __restrict__ bsum, int* __restrict__ boff) {
  __shared__ int ls[512];
  int t = threadIdx.x;
  int v = (t < NBLK) ? bsum[t] : 0;
  ls[t] = v;
  __syncthreads();
  for (int s = 1; s < 512; s <<= 1) {
    int add = (t >= s) ? ls[t - s] : 0;
    __syncthreads();
    ls[t] += add;
    __syncthreads();
  }
  if (t < NBLK) boff[t] = ls[t] - v;  // exclusive
}

__global__ void k_scan_final(const float* __restrict__ deg, const int* __restrict__ boff,
                             int* __restrict__ off) {
  __shared__ int ls[SCAN_BT];
  int b = blockIdx.x, t = threadIdx.x;
  int i = b * SCAN_BT + t;
  int v = (i < NNODES) ? (int)deg[i] - 1 : 0;
  ls[t] = v;
  __syncthreads();
  for (int s = 1; s < SCAN_BT; s <<= 1) {
    int add = (t >= s) ? ls[t - s] : 0;
    __syncthreads();
    ls[t] += add;
    __syncthreads();
  }
  if (i < NNODES) off[i] = boff[b] + ls[t] - v;  // exclusive offset
  if (i == NNODES - 1) off[NNODES] = boff[b] + ls[t];
}

__global__ void k_fill(const int* __restrict__ src, const int* __restrict__ dst,
                       const int* __restrict__ off, int* __restrict__ cursor,
                       int* __restrict__ csr) {
  int i = blockIdx.x * blockDim.x + threadIdx.x;
  if (i < NEDGES) {
    int d = dst[i];
    int p = atomicAdd(&cursor[d], 1);
    csr[off[d] + p] = src[i];
  }
}

// ---------------- skinny GEMM: out[N x 64] = act(A[N x K]) @ W[K x 64] -------
// Epilogue scales by dis[row] (symmetric norm folded into the stored matrix).

template <int K, bool BN>
__global__ void k_gemm(const float* __restrict__ A, const float* __restrict__ W,
                       const float* __restrict__ sc, const float* __restrict__ sh,
                       const float* __restrict__ dis, float* __restrict__ out) {
  int row = blockIdx.x * blockDim.x + threadIdx.x;
  if (row >= NNODES) return;
  float acc[FH];
#pragma unroll
  for (int j = 0; j < FH; ++j) acc[j] = 0.0f;
  const float* a = A + (long long)row * K;
  for (int k = 0; k < K; k += 4) {
    float4 x4 = *(const float4*)(a + k);
    float xs[4] = {x4.x, x4.y, x4.z, x4.w};
#pragma unroll
    for (int kk = 0; kk < 4; ++kk) {
      float xv = xs[kk];
      if (BN) {
        xv = fmaf(xv, sc[k + kk], sh[k + kk]);
        xv = fmaxf(xv, 0.0f);
      }
      const float* wr = W + (k + kk) * FH;
#pragma unroll
      for (int j = 0; j < FH; ++j) acc[j] = fmaf(xv, wr[j], acc[j]);
    }
  }
  float d = dis[row];
  float* o = out + (long long)row * FH;
#pragma unroll
  for (int j = 0; j < FH; j += 4) {
    float4 v = {acc[j] * d, acc[j + 1] * d, acc[j + 2] * d, acc[j + 3] * d};
    *(float4*)(o + j) = v;
  }
}

// ---------------- aggregation: out[d] = dis[d] * (hs[d] + sum hs[csr]) ------
// One wave per dst node, split into 4 groups x 16 lanes; each lane carries a
// float4 (group covers the full 256B row). Group g walks neighbor slots
// {b+g, b+g+4} + 8j -> one dwordx4 instruction fetches 4 DIFFERENT rows (1KB),
// 2 independent chains per group per iteration. Loop count is wave-uniform
// (one node per wave); tails via clamp+select (no branches). Cross-group
// reduce = 2 shfl_xor steps. BN stats fused.

__global__ void k_gather(const float* __restrict__ hs, const int* __restrict__ csr,
                         const int* __restrict__ off, const float* __restrict__ dis,
                         float* __restrict__ out, float* __restrict__ stats) {
  __shared__ float ls[2 * FH];
  int tid = threadIdx.x;
  if (tid < 2 * FH) ls[tid] = 0.0f;
  __syncthreads();
  int lane = tid & 63;
  int g = lane >> 4;   // neighbor group 0..3
  int i = lane & 15;   // feature-quad index: features [4i, 4i+3]
  int wid = (blockIdx.x * blockDim.x + tid) >> 6;
  int nw = (gridDim.x * blockDim.x) >> 6;
  float s1x = 0, s1y = 0, s1z = 0, s1w = 0;
  float s2x = 0, s2y = 0, s2z = 0, s2w = 0;
  for (int d = wid; d < NNODES; d += nw) {
    int b = off[d], e = off[d + 1];
    // self-loop term: all groups load the same row (L1 broadcast), mask to g0
    float4 self = *(const float4*)(hs + (long long)d * FH + i * 4);
    float ax = (g == 0) ? self.x : 0.0f;
    float ay = (g == 0) ? self.y : 0.0f;
    float az = (g == 0) ? self.z : 0.0f;
    float aw = (g == 0) ? self.w : 0.0f;
    int niter = (e - b + 7) >> 3;  // wave-uniform
    int last = e - 1;
    int k0 = b + g;
    for (int j = 0; j < niter; ++j) {
      int idx0 = k0 + 8 * j;
      int idx1 = idx0 + 4;
      int c0 = csr[min(idx0, last)];
      int c1 = csr[min(idx1, last)];
      float4 v0 = *(const float4*)(hs + (long long)c0 * FH + i * 4);
      float4 v1 = *(const float4*)(hs + (long long)c1 * FH + i * 4);
      bool ok0 = idx0 <= last, ok1 = idx1 <= last;
      ax += (ok0 ? v0.x : 0.0f) + (ok1 ? v1.x : 0.0f);
      ay += (ok0 ? v0.y : 0.0f) + (ok1 ? v1.y : 0.0f);
      az += (ok0 ? v0.z : 0.0f) + (ok1 ? v1.z : 0.0f);
      aw += (ok0 ? v0.w : 0.0f) + (ok1 ? v1.w : 0.0f);
    }
    // reduce across the 4 groups (lane bits 4,5)
    ax += __shfl_xor(ax, 16); ax += __shfl_xor(ax, 32);
    ay += __shfl_xor(ay, 16); ay += __shfl_xor(ay, 32);
    az += __shfl_xor(az, 16); az += __shfl_xor(az, 32);
    aw += __shfl_xor(aw, 16); aw += __shfl_xor(aw, 32);
    float dd = dis[d];
    float ox = ax * dd, oy = ay * dd, oz = az * dd, ow = aw * dd;
    if (g == 0) {
      float4 o4 = {ox, oy, oz, ow};
      *(float4*)(out + (long long)d * FH + i * 4) = o4;
    }
    s1x += ox; s2x += ox * ox;
    s1y += oy; s2y += oy * oy;
    s1z += oz; s2z += oz * oz;
    s1w += ow; s2w += ow * ow;
  }
  if (g == 0) {  // group-0 lanes hold one copy of the per-feature sums
    atomicAdd(&ls[i * 4 + 0], s1x);
    atomicAdd(&ls[i * 4 + 1], s1y);
    atomicAdd(&ls[i * 4 + 2], s1z);
    atomicAdd(&ls[i * 4 + 3], s1w);
    atomicAdd(&ls[FH + i * 4 + 0], s2x);
    atomicAdd(&ls[FH + i * 4 + 1], s2y);
    atomicAdd(&ls[FH + i * 4 + 2], s2z);
    atomicAdd(&ls[FH + i * 4 + 3], s2w);
  }
  __syncthreads();
  if (tid < 2 * FH) atomicAdd(&stats[tid], ls[tid]);
}

__global__ void k_bn_finalize(const float* __restrict__ stats, const float* __restrict__ gamma,
                              const float* __restrict__ beta, float* __restrict__ scsh) {
  int f = threadIdx.x;
  if (f < FH) {
    float mean = stats[f] * (1.0f / NNODES);
    float var = stats[FH + f] * (1.0f / NNODES) - mean * mean;
    float s = gamma[f] * rsqrtf(var + EPSV);
    scsh[f] = s;
    scsh[FH + f] = beta[f] - mean * s;  // bias b cancels in training-mode BN
  }
}

// ---------------- pooling (applies BN2+ReLU on load) ----------------

#define POOL_WAVES 1024

__global__ void k_pool(const float* __restrict__ h, const int* __restrict__ batch,
                       const float* __restrict__ scsh, float* __restrict__ pooled,
                       float* __restrict__ cnt) {
  const int CHUNK = (NNODES + POOL_WAVES - 1) / POOL_WAVES;
  int lane = threadIdx.x & 63;
  int wid = (blockIdx.x * blockDim.x + threadIdx.x) >> 6;
  int start = wid * CHUNK;
  if (start >= NNODES) return;
  int end = min(start + CHUNK, NNODES);
  float sc = scsh[lane], sh = scsh[FH + lane];
  int cur = batch[start];  // wave-uniform
  float acc = 0.0f;
  int cl = 0;
  for (int n = start; n < end; ++n) {
    int g = batch[n];
    if (g != cur) {  // uniform branch
      atomicAdd(&pooled[cur * FH + lane], acc);
      if (lane == 0) atomicAdd(&cnt[cur], (float)cl);
      acc = 0.0f;
      cl = 0;
      cur = g;
    }
    float v = fmaf(h[(long long)n * FH + lane], sc, sh);
    acc += fmaxf(v, 0.0f);
    ++cl;
  }
  atomicAdd(&pooled[cur * FH + lane], acc);
  if (lane == 0) atomicAdd(&cnt[cur], (float)cl);
}

// ---------------- final linear: out[G x 32] = (pooled/cnt) @ linW + linb -----

__global__ void k_final(const float* __restrict__ pooled, const float* __restrict__ cnt,
                        const float* __restrict__ linW, const float* __restrict__ linb,
                        float* __restrict__ out) {
  int t = blockIdx.x * blockDim.x + threadIdx.x;
  if (t >= NGRAPH * FOUT) return;
  int g = t / FOUT, o = t % FOUT;
  float inv = 1.0f / fmaxf(cnt[g], 1.0f);
  float acc = linb[o];
#pragma unroll
  for (int k = 0; k < FH; ++k) acc = fmaf(pooled[g * FH + k] * inv, linW[k * FOUT + o], acc);
  out[t] = acc;
}

extern "C" void kernel_launch(void* const* d_in, const int* in_sizes, int n_in,
                              void* d_out, int out_size, void* d_ws, size_t ws_size,
                              hipStream_t stream) {
  const float* x = (const float*)d_in[0];
  const int* edge_index = (const int*)d_in[1];
  const int* batch = (const int*)d_in[2];
  const float* W1 = (const float*)d_in[3];
  // d_in[4] = b1 (cancels in BN), d_in[6] = b2 (cancels in BN)
  const float* W2 = (const float*)d_in[5];
  const float* gamma = (const float*)d_in[7];
  const float* beta = (const float*)d_in[8];
  const float* linW = (const float*)d_in[9];
  const float* linb = (const float*)d_in[10];
  float* out = (float*)d_out;

  const int* esrc = edge_index;           // edge_index[0, :]
  const int* edst = edge_index + NEDGES;  // edge_index[1, :]

  // workspace layout
  float* bufA = (float*)d_ws;                   // N*64 (GEMM output, dis-scaled)
  float* bufB = bufA + (long long)NNODES * FH;  // N*64 (aggregation output)
  float* dis = bufB + (long long)NNODES * FH;   // N (deg -> rsqrt(deg))
  int* off = (int*)(dis + NNODES);              // N+1
  int* csr = off + (NNODES + 1);                // E
  int* bsum = csr + NEDGES;                     // NBLK
  int* boff = bsum + NBLK;                      // NBLK
  int* cursor = boff + NBLK;                    // N   --- zeroed region start
  float* stats1 = (float*)(cursor + NNODES);    // 128
  float* scsh1 = stats1 + 2 * FH;               // 128
  float* stats2 = scsh1 + 2 * FH;               // 128
  float* scsh2 = stats2 + 2 * FH;               // 128
  float* pooled = scsh2 + 2 * FH;               // G*64
  float* cnt = pooled + NGRAPH * FH;            // G   --- zeroed region end

  const int BT = 256;
  const int gN = (NNODES + BT - 1) / BT;
  const int gE = (NEDGES + BT - 1) / BT;

  // zero cursor + stats + pooled + cnt in one shot (contiguous)
  hipMemsetAsync(cursor, 0,
                 (size_t)(NNODES + 4 * 2 * FH + NGRAPH * FH + NGRAPH) * sizeof(float), stream);

  // degrees (raw), CSR offsets, then rsqrt in place, then fill
  k_init_deg<<<gN, BT, 0, stream>>>(dis);
  k_deg_accum<<<gE, BT, 0, stream>>>(edst, dis);
  k_blocksum<<<NBLK, SCAN_BT, 0, stream>>>(dis, bsum);
  k_scan_bsums<<<1, 512, 0, stream>>>(bsum, boff);
  k_scan_final<<<NBLK, SCAN_BT, 0, stream>>>(dis, boff, off);
  k_rsqrt<<<gN, BT, 0, stream>>>(dis);
  k_fill<<<gE, BT, 0, stream>>>(esrc, edst, off, cursor, csr);

  // layer 1
  k_gemm<FIN, false><<<gN, BT, 0, stream>>>(x, W1, nullptr, nullptr, dis, bufA);
  k_gather<<<2048, BT, 0, stream>>>(bufA, csr, off, dis, bufB, stats1);
  k_bn_finalize<<<1, 64, 0, stream>>>(stats1, gamma, beta, scsh1);

  // layer 2 (BN1+ReLU fused into GEMM input load)
  k_gemm<FH, true><<<gN, BT, 0, stream>>>(bufB, W2, scsh1, scsh1 + FH, dis, bufA);
  k_gather<<<2048, BT, 0, stream>>>(bufA, csr, off, dis, bufB, stats2);
  k_bn_finalize<<<1, 64, 0, stream>>>(stats2, gamma, beta, scsh2);

  // pooling (BN2+ReLU fused) + final linear
  k_pool<<<POOL_WAVES * 64 / BT, BT, 0, stream>>>(bufB, batch, scsh2, pooled, cnt);
  k_final<<<(NGRAPH * FOUT + BT - 1) / BT, BT, 0, stream>>>(pooled, cnt, linW, linb, out);
}

// Round 7
// 560.590 us; speedup vs baseline: 1.3226x; 1.0311x over previous
//
#include <hip/hip_runtime.h>

#define NNODES 100000
#define NEDGES 1600000
#define FIN 128
#define FH 64
#define FOUT 32
#define NGRAPH 128
#define EPSV 1e-5f

#define SCAN_BT 256
#define NBLK ((NNODES + SCAN_BT - 1) / SCAN_BT)  // 391

typedef unsigned short ushort_t;

// ---- bf16 helpers (RNE) ----
__device__ inline unsigned f2bf(float f) {
  union { float f; unsigned u; } x;
  x.f = f;
  return (x.u + 0x7fffu + ((x.u >> 16) & 1u)) >> 16;
}
__device__ inline unsigned pack2(float a, float b) { return f2bf(a) | (f2bf(b) << 16); }
__device__ inline float bflo(unsigned u) {
  union { unsigned u; float f; } x;
  x.u = u << 16;
  return x.f;
}
__device__ inline float bfhi(unsigned u) {
  union { unsigned u; float f; } x;
  x.u = u & 0xffff0000u;
  return x.f;
}

// ---------------- degree / normalization ----------------

__global__ void k_init_deg(float* __restrict__ deg) {
  int i = blockIdx.x * blockDim.x + threadIdx.x;
  if (i < NNODES) deg[i] = 1.0f;  // self-loop contributes 1
}

__global__ void k_deg_accum(const int* __restrict__ dst, float* __restrict__ deg) {
  int i = blockIdx.x * blockDim.x + threadIdx.x;
  if (i < NEDGES) atomicAdd(&deg[dst[i]], 1.0f);
}

__global__ void k_rsqrt(float* __restrict__ deg) {
  int i = blockIdx.x * blockDim.x + threadIdx.x;
  if (i < NNODES) deg[i] = rsqrtf(deg[i]);  // deg >= 1 always
}

// ---------------- CSR build: hierarchical exclusive scan of in-degrees ------

__global__ void k_blocksum(const float* __restrict__ deg, int* __restrict__ bsum) {
  __shared__ int ls[SCAN_BT];
  int b = blockIdx.x, t = threadIdx.x;
  int i = b * SCAN_BT + t;
  ls[t] = (i < NNODES) ? (int)deg[i] - 1 : 0;
  __syncthreads();
  for (int s = SCAN_BT / 2; s > 0; s >>= 1) {
    if (t < s) ls[t] += ls[t + s];
    __syncthreads();
  }
  if (t == 0) bsum[b] = ls[0];
}

__global__ void k_scan_bsums(const int* __restrict__ bsum, int* __restrict__ boff) {
  __shared__ int ls[512];
  int t = threadIdx.x;
  int v = (t < NBLK) ? bsum[t] : 0;
  ls[t] = v;
  __syncthreads();
  for (int s = 1; s < 512; s <<= 1) {
    int add = (t >= s) ? ls[t - s] : 0;
    __syncthreads();
    ls[t] += add;
    __syncthreads();
  }
  if (t < NBLK) boff[t] = ls[t] - v;  // exclusive
}

__global__ void k_scan_final(const float* __restrict__ deg, const int* __restrict__ boff,
                             int* __restrict__ off) {
  __shared__ int ls[SCAN_BT];
  int b = blockIdx.x, t = threadIdx.x;
  int i = b * SCAN_BT + t;
  int v = (i < NNODES) ? (int)deg[i] - 1 : 0;
  ls[t] = v;
  __syncthreads();
  for (int s = 1; s < SCAN_BT; s <<= 1) {
    int add = (t >= s) ? ls[t - s] : 0;
    __syncthreads();
    ls[t] += add;
    __syncthreads();
  }
  if (i < NNODES) off[i] = boff[b] + ls[t] - v;  // exclusive offset
  if (i == NNODES - 1) off[NNODES] = boff[b] + ls[t];
}

// XCD-partitioned fill: blocks of class (blockIdx&7) handle only dst in their
// 12500-node slice -> each csr line / cursor counter is owned by ONE XCD's L2
// (no cross-XCD line ping-pong; write amplification ~16x -> ~1x). dst array is
// read 8x (coalesced, cheap).

__global__ void k_fill(const int* __restrict__ src, const int* __restrict__ dst,
                       const int* __restrict__ off, int* __restrict__ cursor,
                       int* __restrict__ csr) {
  const int SLICE = NNODES / 8;  // 12500
  int xcd = blockIdx.x & 7;
  int lo = xcd * SLICE, hi = lo + SLICE;
  int chunk = blockIdx.x >> 3;
  int nchunk = gridDim.x >> 3;
  for (int i = chunk * blockDim.x + threadIdx.x; i < NEDGES; i += nchunk * blockDim.x) {
    int d = dst[i];
    if (d >= lo && d < hi) {
      int p = atomicAdd(&cursor[d], 1);
      csr[off[d] + p] = src[i];
    }
  }
}

// ---------------- skinny GEMM: out[N x 64] = act(A[N x K]) @ W[K x 64] -------
// Epilogue scales by dis[row] and stores bf16 (halves gather traffic).

template <int K, bool BN>
__global__ void k_gemm(const float* __restrict__ A, const float* __restrict__ W,
                       const float* __restrict__ sc, const float* __restrict__ sh,
                       const float* __restrict__ dis, ushort_t* __restrict__ out) {
  int row = blockIdx.x * blockDim.x + threadIdx.x;
  if (row >= NNODES) return;
  float acc[FH];
#pragma unroll
  for (int j = 0; j < FH; ++j) acc[j] = 0.0f;
  const float* a = A + (long long)row * K;
  for (int k = 0; k < K; k += 4) {
    float4 x4 = *(const float4*)(a + k);
    float xs[4] = {x4.x, x4.y, x4.z, x4.w};
#pragma unroll
    for (int kk = 0; kk < 4; ++kk) {
      float xv = xs[kk];
      if (BN) {
        xv = fmaf(xv, sc[k + kk], sh[k + kk]);
        xv = fmaxf(xv, 0.0f);
      }
      const float* wr = W + (k + kk) * FH;
#pragma unroll
      for (int j = 0; j < FH; ++j) acc[j] = fmaf(xv, wr[j], acc[j]);
    }
  }
  float d = dis[row];
  ushort_t* o = out + (long long)row * FH;
#pragma unroll
  for (int j = 0; j < FH; j += 8) {
    uint4 v;
    v.x = pack2(acc[j] * d, acc[j + 1] * d);
    v.y = pack2(acc[j + 2] * d, acc[j + 3] * d);
    v.z = pack2(acc[j + 4] * d, acc[j + 5] * d);
    v.w = pack2(acc[j + 6] * d, acc[j + 7] * d);
    *(uint4*)(o + j) = v;
  }
}

// ---------------- aggregation: out[d] = dis[d] * (hs[d] + sum hs[csr]) ------
// hs is bf16 (128B rows). Wave = 4 groups x 16 lanes; each lane loads uint2
// (4 bf16 feats). Group g walks slots {b+g+4t} stride 16 -> 4 independent row
// chains per group per iteration (16 edges/iter/wave). Uniform trip count,
// tails via clamp+select. fp32 accumulation; fp32 output. BN stats fused.

__global__ void k_gather(const ushort_t* __restrict__ hs, const int* __restrict__ csr,
                         const int* __restrict__ off, const float* __restrict__ dis,
                         float* __restrict__ out, float* __restrict__ stats) {
  __shared__ float ls[2 * FH];
  int tid = threadIdx.x;
  if (tid < 2 * FH) ls[tid] = 0.0f;
  __syncthreads();
  int lane = tid & 63;
  int g = lane >> 4;  // neighbor group 0..3
  int i = lane & 15;  // feature-quad: features [4i, 4i+3]
  int wid = (blockIdx.x * blockDim.x + tid) >> 6;
  int nw = (gridDim.x * blockDim.x) >> 6;
  float s1x = 0, s1y = 0, s1z = 0, s1w = 0;
  float s2x = 0, s2y = 0, s2z = 0, s2w = 0;
  for (int d = wid; d < NNODES; d += nw) {
    int b = off[d], e = off[d + 1];
    uint2 su = *(const uint2*)(hs + (long long)d * FH + i * 4);
    float ax = (g == 0) ? bflo(su.x) : 0.0f;
    float ay = (g == 0) ? bfhi(su.x) : 0.0f;
    float az = (g == 0) ? bflo(su.y) : 0.0f;
    float aw = (g == 0) ? bfhi(su.y) : 0.0f;
    int niter = (e - b + 15) >> 4;  // wave-uniform
    int last = e - 1;
    int k0 = b + g;
    for (int j = 0; j < niter; ++j) {
      int i0 = k0 + 16 * j, i1 = i0 + 4, i2 = i0 + 8, i3 = i0 + 12;
      int c0 = csr[min(i0, last)];
      int c1 = csr[min(i1, last)];
      int c2 = csr[min(i2, last)];
      int c3 = csr[min(i3, last)];
      uint2 u0 = *(const uint2*)(hs + (long long)c0 * FH + i * 4);
      uint2 u1 = *(const uint2*)(hs + (long long)c1 * FH + i * 4);
      uint2 u2 = *(const uint2*)(hs + (long long)c2 * FH + i * 4);
      uint2 u3 = *(const uint2*)(hs + (long long)c3 * FH + i * 4);
      bool k0ok = i0 <= last, k1ok = i1 <= last, k2ok = i2 <= last, k3ok = i3 <= last;
      ax += (k0ok ? bflo(u0.x) : 0.0f) + (k1ok ? bflo(u1.x) : 0.0f) +
            (k2ok ? bflo(u2.x) : 0.0f) + (k3ok ? bflo(u3.x) : 0.0f);
      ay += (k0ok ? bfhi(u0.x) : 0.0f) + (k1ok ? bfhi(u1.x) : 0.0f) +
            (k2ok ? bfhi(u2.x) : 0.0f) + (k3ok ? bfhi(u3.x) : 0.0f);
      az += (k0ok ? bflo(u0.y) : 0.0f) + (k1ok ? bflo(u1.y) : 0.0f) +
            (k2ok ? bflo(u2.y) : 0.0f) + (k3ok ? bflo(u3.y) : 0.0f);
      aw += (k0ok ? bfhi(u0.y) : 0.0f) + (k1ok ? bfhi(u1.y) : 0.0f) +
            (k2ok ? bfhi(u2.y) : 0.0f) + (k3ok ? bfhi(u3.y) : 0.0f);
    }
    // reduce across the 4 groups (lane bits 4,5) — butterfly, all lanes get sum
    ax += __shfl_xor(ax, 16); ax += __shfl_xor(ax, 32);
    ay += __shfl_xor(ay, 16); ay += __shfl_xor(ay, 32);
    az += __shfl_xor(az, 16); az += __shfl_xor(az, 32);
    aw += __shfl_xor(aw, 16); aw += __shfl_xor(aw, 32);
    float dd = dis[d];
    float ox = ax * dd, oy = ay * dd, oz = az * dd, ow = aw * dd;
    if (g == 0) {
      float4 o4 = {ox, oy, oz, ow};
      *(float4*)(out + (long long)d * FH + i * 4) = o4;
    }
    s1x += ox; s2x += ox * ox;
    s1y += oy; s2y += oy * oy;
    s1z += oz; s2z += oz * oz;
    s1w += ow; s2w += ow * ow;
  }
  if (g == 0) {  // group-0 lanes hold one copy of the per-feature sums
    atomicAdd(&ls[i * 4 + 0], s1x);
    atomicAdd(&ls[i * 4 + 1], s1y);
    atomicAdd(&ls[i * 4 + 2], s1z);
    atomicAdd(&ls[i * 4 + 3], s1w);
    atomicAdd(&ls[FH + i * 4 + 0], s2x);
    atomicAdd(&ls[FH + i * 4 + 1], s2y);
    atomicAdd(&ls[FH + i * 4 + 2], s2z);
    atomicAdd(&ls[FH + i * 4 + 3], s2w);
  }
  __syncthreads();
  if (tid < 2 * FH) atomicAdd(&stats[tid], ls[tid]);
}

__global__ void k_bn_finalize(const float* __restrict__ stats, const float* __restrict__ gamma,
                              const float* __restrict__ beta, float* __restrict__ scsh) {
  int f = threadIdx.x;
  if (f < FH) {
    float mean = stats[f] * (1.0f / NNODES);
    float var = stats[FH + f] * (1.0f / NNODES) - mean * mean;
    float s = gamma[f] * rsqrtf(var + EPSV);
    scsh[f] = s;
    scsh[FH + f] = beta[f] - mean * s;  // bias b cancels in training-mode BN
  }
}

// ---------------- pooling (applies BN2+ReLU on load) ----------------

#define POOL_WAVES 1024

__global__ void k_pool(const float* __restrict__ h, const int* __restrict__ batch,
                       const float* __restrict__ scsh, float* __restrict__ pooled,
                       float* __restrict__ cnt) {
  const int CHUNK = (NNODES + POOL_WAVES - 1) / POOL_WAVES;
  int lane = threadIdx.x & 63;
  int wid = (blockIdx.x * blockDim.x + threadIdx.x) >> 6;
  int start = wid * CHUNK;
  if (start >= NNODES) return;
  int end = min(start + CHUNK, NNODES);
  float sc = scsh[lane], sh = scsh[FH + lane];
  int cur = batch[start];  // wave-uniform
  float acc = 0.0f;
  int cl = 0;
  for (int n = start; n < end; ++n) {
    int g = batch[n];
    if (g != cur) {  // uniform branch
      atomicAdd(&pooled[cur * FH + lane], acc);
      if (lane == 0) atomicAdd(&cnt[cur], (float)cl);
      acc = 0.0f;
      cl = 0;
      cur = g;
    }
    float v = fmaf(h[(long long)n * FH + lane], sc, sh);
    acc += fmaxf(v, 0.0f);
    ++cl;
  }
  atomicAdd(&pooled[cur * FH + lane], acc);
  if (lane == 0) atomicAdd(&cnt[cur], (float)cl);
}

// ---------------- final linear: out[G x 32] = (pooled/cnt) @ linW + linb -----

__global__ void k_final(const float* __restrict__ pooled, const float* __restrict__ cnt,
                        const float* __restrict__ linW, const float* __restrict__ linb,
                        float* __restrict__ out) {
  int t = blockIdx.x * blockDim.x + threadIdx.x;
  if (t >= NGRAPH * FOUT) return;
  int g = t / FOUT, o = t % FOUT;
  float inv = 1.0f / fmaxf(cnt[g], 1.0f);
  float acc = linb[o];
#pragma unroll
  for (int k = 0; k < FH; ++k) acc = fmaf(pooled[g * FH + k] * inv, linW[k * FOUT + o], acc);
  out[t] = acc;
}

extern "C" void kernel_launch(void* const* d_in, const int* in_sizes, int n_in,
                              void* d_out, int out_size, void* d_ws, size_t ws_size,
                              hipStream_t stream) {
  const float* x = (const float*)d_in[0];
  const int* edge_index = (const int*)d_in[1];
  const int* batch = (const int*)d_in[2];
  const float* W1 = (const float*)d_in[3];
  // d_in[4] = b1 (cancels in BN), d_in[6] = b2 (cancels in BN)
  const float* W2 = (const float*)d_in[5];
  const float* gamma = (const float*)d_in[7];
  const float* beta = (const float*)d_in[8];
  const float* linW = (const float*)d_in[9];
  const float* linb = (const float*)d_in[10];
  float* out = (float*)d_out;

  const int* esrc = edge_index;           // edge_index[0, :]
  const int* edst = edge_index + NEDGES;  // edge_index[1, :]

  // workspace layout (bufA region kept float-sized; used as bf16)
  ushort_t* bufA = (ushort_t*)d_ws;                        // N*64 bf16 (GEMM out, dis-scaled)
  float* bufB = (float*)d_ws + (long long)NNODES * FH;     // N*64 fp32 (aggregation output)
  float* dis = bufB + (long long)NNODES * FH;              // N
  int* off = (int*)(dis + NNODES);                         // N+1
  int* csr = off + (NNODES + 1);                           // E
  int* bsum = csr + NEDGES;                                // NBLK
  int* boff = bsum + NBLK;                                 // NBLK
  int* cursor = boff + NBLK;                               // N   --- zeroed region start
  float* stats1 = (float*)(cursor + NNODES);               // 128
  float* scsh1 = stats1 + 2 * FH;                          // 128
  float* stats2 = scsh1 + 2 * FH;                          // 128
  float* scsh2 = stats2 + 2 * FH;                          // 128
  float* pooled = scsh2 + 2 * FH;                          // G*64
  float* cnt = pooled + NGRAPH * FH;                       // G   --- zeroed region end

  const int BT = 256;
  const int gN = (NNODES + BT - 1) / BT;
  const int gE = (NEDGES + BT - 1) / BT;

  // zero cursor + stats + pooled + cnt in one shot (contiguous)
  hipMemsetAsync(cursor, 0,
                 (size_t)(NNODES + 4 * 2 * FH + NGRAPH * FH + NGRAPH) * sizeof(float), stream);

  // degrees (raw), CSR offsets, then rsqrt in place, then XCD-partitioned fill
  k_init_deg<<<gN, BT, 0, stream>>>(dis);
  k_deg_accum<<<gE, BT, 0, stream>>>(edst, dis);
  k_blocksum<<<NBLK, SCAN_BT, 0, stream>>>(dis, bsum);
  k_scan_bsums<<<1, 512, 0, stream>>>(bsum, boff);
  k_scan_final<<<NBLK, SCAN_BT, 0, stream>>>(dis, boff, off);
  k_rsqrt<<<gN, BT, 0, stream>>>(dis);
  k_fill<<<2048, BT, 0, stream>>>(esrc, edst, off, cursor, csr);

  // layer 1
  k_gemm<FIN, false><<<gN, BT, 0, stream>>>(x, W1, nullptr, nullptr, dis, bufA);
  k_gather<<<2048, BT, 0, stream>>>(bufA, csr, off, dis, bufB, stats1);
  k_bn_finalize<<<1, 64, 0, stream>>>(stats1, gamma, beta, scsh1);

  // layer 2 (BN1+ReLU fused into GEMM input load)
  k_gemm<FH, true><<<gN, BT, 0, stream>>>(bufB, W2, scsh1, scsh1 + FH, dis, bufA);
  k_gather<<<2048, BT, 0, stream>>>(bufA, csr, off, dis, bufB, stats2);
  k_bn_finalize<<<1, 64, 0, stream>>>(stats2, gamma, beta, scsh2);

  // pooling (BN2+ReLU fused) + final linear
  k_pool<<<POOL_WAVES * 64 / BT, BT, 0, stream>>>(bufB, batch, scsh2, pooled, cnt);
  k_final<<<(NGRAPH * FOUT + BT - 1) / BT, BT, 0, stream>>>(pooled, cnt, linW, linb, out);
}